// Round 6
// baseline (501.856 us; speedup 1.0000x reference)
//
#include <hip/hip_runtime.h>
#include <math.h>

#define NUM_USERS 100000
#define NUM_ITEMS 50000
#define NN 150000
#define DD 64
#define EE 1250000
#define SS 400000
#define TAU 0.2f
#define EDGE_BIAS 0.5f

#define NBUCKET 586     // coarse buckets (row >> 8)
#define NB1 153         // partition blocks
#define TILE 8192       // edges per partition block (153*8192 >= EE)
#define GN (NBUCKET * NB1)        // 89658 ghist entries
#define GB ((GN + 255) / 256)     // 351 scan blocks

typedef __attribute__((ext_vector_type(8))) _Float16 f16x8;
typedef __attribute__((ext_vector_type(2))) _Float16 f16x2;
typedef __attribute__((ext_vector_type(4))) float f32x4;
typedef __attribute__((ext_vector_type(4))) unsigned int u32x4;
typedef __attribute__((ext_vector_type(4))) int i32x4;

#define LDW 136  // f16 LDS row stride for gate W1 prologue

// bf16 helpers (RNE, finite inputs)
__device__ __forceinline__ unsigned int pack_bf16(float lo, float hi) {
    unsigned int a = __float_as_uint(lo), b = __float_as_uint(hi);
    a += 0x7fffu + ((a >> 16) & 1u);
    b += 0x7fffu + ((b >> 16) & 1u);
    return (a >> 16) | (b & 0xffff0000u);
}
__device__ __forceinline__ float bf_lo(unsigned int u) { return __uint_as_float(u << 16); }
__device__ __forceinline__ float bf_hi(unsigned int u) { return __uint_as_float(u & 0xffff0000u); }

// ---------------------------------------------------------------------------
// init: half-width z0 (chains identical at l=0), f16 ego copy for gate,
// winner=-1, rowptr[NN], gate_sum=0.
// ---------------------------------------------------------------------------
__global__ void init_kernel(const float* __restrict__ user, const float* __restrict__ item,
                            unsigned int* __restrict__ z0h, _Float16* __restrict__ ego16,
                            int* __restrict__ winner, int* __restrict__ rowptr,
                            double* __restrict__ gate_sum) {
    int j = blockIdx.x * blockDim.x + threadIdx.x;
    if (j < NN * 32) {
        int n = j >> 5, dp = j & 31;
        const float* ego = (n < NUM_USERS) ? user + (size_t)n * 64
                                           : item + (size_t)(n - NUM_USERS) * 64;
        float2 e = *(const float2*)(ego + 2 * dp);
        z0h[j] = pack_bf16(e.x, e.y);
        f16x2 h;
        h[0] = (_Float16)e.x;
        h[1] = (_Float16)e.y;
        *(f16x2*)(ego16 + (size_t)n * 64 + 2 * dp) = h;
    }
    if (j < EE) winner[j] = -1;
    if (j == 0) { rowptr[NN] = EE; *gate_sum = 0.0; }
}

// ---------------------------------------------------------------------------
// gate MLP via f16 MFMA, barrier-free direct-gather, fast-math epilogue
// (unchanged from round 5)
// ---------------------------------------------------------------------------
__global__ __launch_bounds__(256) void gate_kernel(
        const _Float16* __restrict__ ego16,
        const int* __restrict__ rows, const int* __restrict__ cols,
        const int* __restrict__ sidx, const float* __restrict__ eps,
        const float* __restrict__ W1, const float* __restrict__ b1,
        const float* __restrict__ W2, const float* __restrict__ b2,
        float* __restrict__ gate, double* __restrict__ gate_sum) {
    __shared__ _Float16 sh[64 * LDW];
    __shared__ double sdq[4];

    const int t    = threadIdx.x;
    const int lane = t & 63;
    const int w    = t >> 6;
    const int col  = lane & 15;
    const int quad = lane >> 4;

    for (int idx = t; idx < 8192; idx += 256) {
        int k = idx >> 6, n = idx & 63;
        sh[n * LDW + k] = (_Float16)W1[idx];
    }
    float b1v[4];
#pragma unroll
    for (int nt = 0; nt < 4; ++nt) b1v[nt] = b1[nt * 16 + col];
    float w2v[4];
#pragma unroll
    for (int nt = 0; nt < 4; ++nt) w2v[nt] = W2[nt * 16 + col];
    const float b2v = b2[0];
    __syncthreads();

    f16x8 bfrag[4][4];
#pragma unroll
    for (int nt = 0; nt < 4; ++nt)
#pragma unroll
        for (int kk = 0; kk < 4; ++kk)
            bfrag[nt][kk] = *(const f16x8*)&sh[(nt * 16 + col) * LDW + kk * 32 + quad * 8];

    double partial = 0.0;
    const int nwaves = gridDim.x * 4;
    const int wid = blockIdx.x * 4 + w;

    for (int grp = wid; grp < SS / 16; grp += nwaves) {
        const int gbase = grp * 16;
        const int sid = sidx[gbase + col];
        const int su = rows[sid];
        const int sv = cols[sid];
        const _Float16* pu = ego16 + (size_t)su * 64 + quad * 8;
        const _Float16* pv = ego16 + (size_t)sv * 64 + quad * 8;
        f16x8 a0 = *(const f16x8*)(pu);
        f16x8 a1 = *(const f16x8*)(pu + 32);
        f16x8 a2 = *(const f16x8*)(pv);
        f16x8 a3 = *(const f16x8*)(pv + 32);

        f32x4 acc[4] = {};
#pragma unroll
        for (int nt = 0; nt < 4; ++nt) {
            acc[nt] = __builtin_amdgcn_mfma_f32_16x16x32_f16(a0, bfrag[nt][0], acc[nt], 0, 0, 0);
            acc[nt] = __builtin_amdgcn_mfma_f32_16x16x32_f16(a1, bfrag[nt][1], acc[nt], 0, 0, 0);
            acc[nt] = __builtin_amdgcn_mfma_f32_16x16x32_f16(a2, bfrag[nt][2], acc[nt], 0, 0, 0);
            acc[nt] = __builtin_amdgcn_mfma_f32_16x16x32_f16(a3, bfrag[nt][3], acc[nt], 0, 0, 0);
        }

        float p[4];
#pragma unroll
        for (int r = 0; r < 4; ++r) {
            float sum = 0.f;
#pragma unroll
            for (int nt = 0; nt < 4; ++nt)
                sum = fmaf(fmaxf(acc[nt][r] + b1v[nt], 0.f), w2v[nt], sum);
#pragma unroll
            for (int off = 8; off >= 1; off >>= 1) sum += __shfl_xor(sum, off);
            p[r] = sum + b2v;
        }
        if (col == 0) {
            const int sb = gbase + quad * 4;
            float4 ev4 = *(const float4*)(eps + sb);
            float g4[4];
            const float evs[4] = {ev4.x, ev4.y, ev4.z, ev4.w};
#pragma unroll
            for (int r = 0; r < 4; ++r) {
                float ev  = evs[r] * (1.f - 2e-6f) + 1e-6f;
                float gum = __logf(ev) - __logf(1.f - ev);
                float zz  = (p[r] + gum) * (1.f / TAU);
                float g   = __builtin_amdgcn_rcpf(1.f + __expf(-zz)) + EDGE_BIAS;
                g4[r] = g;
                partial += (double)g;
            }
            *(float4*)(gate + sb) = make_float4(g4[0], g4[1], g4[2], g4[3]);
        }
    }

#pragma unroll
    for (int off = 32; off >= 1; off >>= 1) partial += __shfl_xor(partial, off);
    if (lane == 0) sdq[w] = partial;
    __syncthreads();
    if (t == 0) atomicAdd(gate_sum, sdq[0] + sdq[1] + sdq[2] + sdq[3]);
}

// ---------------------------------------------------------------------------
// Deterministic radix-partition scatter
// ---------------------------------------------------------------------------
__global__ __launch_bounds__(256) void bucket_count_kernel(
        const int* __restrict__ rows, const int* __restrict__ sidx,
        int* __restrict__ ghist, int* __restrict__ winner) {
    __shared__ int h[NBUCKET];
    const int t = threadIdx.x;
    for (int i = t; i < NBUCKET; i += 256) h[i] = 0;
    __syncthreads();
    const int base = blockIdx.x * TILE;
    const int end = (base + TILE < EE) ? base + TILE : EE;
    for (int i = base + t; i < end; i += 256) atomicAdd(&h[rows[i] >> 8], 1);
    const int gt = blockIdx.x * 256 + t;
    for (int s = gt; s < SS; s += NB1 * 256) atomicMax(&winner[sidx[s]], s);
    __syncthreads();
    for (int i = t; i < NBUCKET; i += 256) ghist[i * NB1 + blockIdx.x] = h[i];
}

__global__ void gscan1_kernel(int* __restrict__ data, int* __restrict__ bsum, int N) {
    __shared__ int sh[256];
    int tid = threadIdx.x;
    int i = blockIdx.x * 256 + tid;
    int v = (i < N) ? data[i] : 0;
    sh[tid] = v;
    __syncthreads();
    for (int off = 1; off < 256; off <<= 1) {
        int tv = (tid >= off) ? sh[tid - off] : 0;
        __syncthreads();
        sh[tid] += tv;
        __syncthreads();
    }
    if (i < N) data[i] = sh[tid] - v;
    if (tid == 255) bsum[blockIdx.x] = sh[255];
}

__global__ void gscan2_kernel(int* __restrict__ bsum, int NB) {
    __shared__ int sh[1024];
    int tid = threadIdx.x;
    int v = (tid < NB) ? bsum[tid] : 0;
    sh[tid] = v;
    __syncthreads();
    for (int off = 1; off < 1024; off <<= 1) {
        int tv = (tid >= off) ? sh[tid - off] : 0;
        __syncthreads();
        sh[tid] += tv;
        __syncthreads();
    }
    if (tid < NB) bsum[tid] = sh[tid] - v;
}

// gscan3 folded into the two consumers below: final prefix = ghist[i] +
// bsum2[i>>8] (saves one launch + one 360KB pass).

__global__ __launch_bounds__(256) void bucket_scatter_kernel(
        const int* __restrict__ rows, const int* __restrict__ cols,
        const float* __restrict__ vals,
        const int* __restrict__ winner, const float* __restrict__ gate,
        const int* __restrict__ ghist, const int* __restrict__ bsum2,
        int4* __restrict__ buf) {
    __shared__ int sbase[NBUCKET];
    const int t = threadIdx.x;
    for (int i = t; i < NBUCKET; i += 256) {
        int idx = i * NB1 + blockIdx.x;
        sbase[i] = ghist[idx] + bsum2[idx >> 8];
    }
    __syncthreads();
    const int base = blockIdx.x * TILE;
    const int end = (base + TILE < EE) ? base + TILE : EE;
    for (int e = base + t; e < end; e += 256) {
        int r = rows[e];
        float v = vals[e];
        int wn = winner[e];
        float mv = (wn >= 0) ? v * gate[wn] : v;
        int pos = atomicAdd(&sbase[r >> 8], 1);
        buf[pos] = make_int4(r, cols[e], __float_as_int(v), __float_as_int(mv));
    }
}

__global__ __launch_bounds__(256) void bucket_to_csr_kernel(
        const int* __restrict__ ghist, const int* __restrict__ bsum2,
        const int4* __restrict__ buf,
        int* __restrict__ rowptr, int4* __restrict__ edata) {
    __shared__ int sh[256];
    const int b = blockIdx.x;
    const int t = threadIdx.x;
    const int i0 = b * NB1;
    const int i1 = (b + 1) * NB1;
    const int rbeg = ghist[i0] + bsum2[i0 >> 8];
    const int rend = (b + 1 < NBUCKET) ? ghist[i1] + bsum2[i1 >> 8] : EE;
    sh[t] = 0;
    __syncthreads();
    for (int i = rbeg + t; i < rend; i += 256) atomicAdd(&sh[buf[i].x & 255], 1);
    __syncthreads();
    int cnt = sh[t];
    for (int off = 1; off < 256; off <<= 1) {
        int tv = (t >= off) ? sh[t - off] : 0;
        __syncthreads();
        sh[t] += tv;
        __syncthreads();
    }
    int rowbase = rbeg + sh[t] - cnt;
    int r = (b << 8) + t;
    if (r < NN) rowptr[r] = rowbase;
    __syncthreads();
    sh[t] = rowbase;
    __syncthreads();
    for (int i = rbeg + t; i < rend; i += 256) {
        int4 ed = buf[i];
        int pos = atomicAdd(&sh[ed.x & 255], 1);
        edata[pos] = make_int4(ed.y, ed.z, ed.w, 0);
    }
}

// ---------------------------------------------------------------------------
// packed dual-chain gather-SpMM. R5 diagnosis: spmm FETCH exceeds the
// mandatory byte budget by ~80MB — sequential streams (edata) and the
// write-allocate output evict the L2/L3-resident gather set. Fix: mark all
// streaming read-once loads and write-once stores non-temporal (nt bit:
// no-allocate/evict-first); keep the random z-gather on the caching path.
// ---------------------------------------------------------------------------
__global__ __launch_bounds__(256) void spmm_packed_kernel(
        const int* __restrict__ rowptr, const int4* __restrict__ edata,
        const unsigned int* __restrict__ zin, unsigned int* __restrict__ zout,
        int zstride, int zmask) {
    int w = (blockIdx.x * blockDim.x + threadIdx.x) >> 6;
    if (w >= NN) return;
    const int lane = threadIdx.x & 63;
    const int g    = lane >> 4;
    const int sub  = lane & 15;
    const int sq   = (sub & zmask) * 4;
    const int beg = rowptr[w], end = rowptr[w + 1];

    float a[8] = {0.f, 0.f, 0.f, 0.f, 0.f, 0.f, 0.f, 0.f};
    int i = beg;
    for (; i + 8 <= end; i += 8) {
        i32x4 e0 = __builtin_nontemporal_load((const i32x4*)(edata + i + g));
        i32x4 e1 = __builtin_nontemporal_load((const i32x4*)(edata + i + 4 + g));
        u32x4 p0 = *(const u32x4*)(zin + (size_t)e0[0] * zstride + sq);
        u32x4 p1 = *(const u32x4*)(zin + (size_t)e1[0] * zstride + sq);
        float w0 = (sub < 8) ? __int_as_float(e0[1]) : __int_as_float(e0[2]);
        float w1 = (sub < 8) ? __int_as_float(e1[1]) : __int_as_float(e1[2]);
        a[0] = fmaf(w0, bf_lo(p0[0]), a[0]); a[1] = fmaf(w0, bf_hi(p0[0]), a[1]);
        a[2] = fmaf(w0, bf_lo(p0[1]), a[2]); a[3] = fmaf(w0, bf_hi(p0[1]), a[3]);
        a[4] = fmaf(w0, bf_lo(p0[2]), a[4]); a[5] = fmaf(w0, bf_hi(p0[2]), a[5]);
        a[6] = fmaf(w0, bf_lo(p0[3]), a[6]); a[7] = fmaf(w0, bf_hi(p0[3]), a[7]);
        a[0] = fmaf(w1, bf_lo(p1[0]), a[0]); a[1] = fmaf(w1, bf_hi(p1[0]), a[1]);
        a[2] = fmaf(w1, bf_lo(p1[1]), a[2]); a[3] = fmaf(w1, bf_hi(p1[1]), a[3]);
        a[4] = fmaf(w1, bf_lo(p1[2]), a[4]); a[5] = fmaf(w1, bf_hi(p1[2]), a[5]);
        a[6] = fmaf(w1, bf_lo(p1[3]), a[6]); a[7] = fmaf(w1, bf_hi(p1[3]), a[7]);
    }
    for (; i < end; i += 4) {
        int idx = i + g;
        i32x4 e = __builtin_nontemporal_load(
            (const i32x4*)(edata + ((idx < end) ? idx : end - 1)));
        float wt = (idx < end) ? ((sub < 8) ? __int_as_float(e[1]) : __int_as_float(e[2])) : 0.f;
        u32x4 p = *(const u32x4*)(zin + (size_t)e[0] * zstride + sq);
        a[0] = fmaf(wt, bf_lo(p[0]), a[0]); a[1] = fmaf(wt, bf_hi(p[0]), a[1]);
        a[2] = fmaf(wt, bf_lo(p[1]), a[2]); a[3] = fmaf(wt, bf_hi(p[1]), a[3]);
        a[4] = fmaf(wt, bf_lo(p[2]), a[4]); a[5] = fmaf(wt, bf_hi(p[2]), a[5]);
        a[6] = fmaf(wt, bf_lo(p[3]), a[6]); a[7] = fmaf(wt, bf_hi(p[3]), a[7]);
    }
#pragma unroll
    for (int j = 0; j < 8; ++j) {
        a[j] += __shfl_xor(a[j], 16);
        a[j] += __shfl_xor(a[j], 32);
    }
    if (lane < 16) {
        u32x4 o;
        o[0] = pack_bf16(a[0], a[1]);
        o[1] = pack_bf16(a[2], a[3]);
        o[2] = pack_bf16(a[4], a[5]);
        o[3] = pack_bf16(a[6], a[7]);
        // zout is re-read (gathered) by the NEXT pass, but streams out of L2
        // long before; keep normal store so L3 retains it.
        *(u32x4*)(zout + (size_t)w * 64 + sub * 4) = o;
    }
}

// ---------------------------------------------------------------------------
// final SpMM layer fused with fold; NT policy: edata/z1/z2-seq/ego reads and
// output stores non-temporal, z2 gather cached.
// ---------------------------------------------------------------------------
__global__ __launch_bounds__(256) void spmm_final_kernel(
        const int* __restrict__ rowptr, const int4* __restrict__ edata,
        const unsigned int* __restrict__ zin,
        const unsigned int* __restrict__ z1, const unsigned int* __restrict__ z2,
        const float* __restrict__ user, const float* __restrict__ item,
        float* __restrict__ outx, float* __restrict__ outy) {
    int w = (blockIdx.x * blockDim.x + threadIdx.x) >> 6;
    if (w >= NN) return;
    const int lane = threadIdx.x & 63;
    const int g    = lane >> 4;
    const int sub  = lane & 15;
    const int beg = rowptr[w], end = rowptr[w + 1];

    float a[8] = {0.f, 0.f, 0.f, 0.f, 0.f, 0.f, 0.f, 0.f};
    int i = beg;
    for (; i + 8 <= end; i += 8) {
        i32x4 e0 = __builtin_nontemporal_load((const i32x4*)(edata + i + g));
        i32x4 e1 = __builtin_nontemporal_load((const i32x4*)(edata + i + 4 + g));
        u32x4 p0 = *(const u32x4*)(zin + (size_t)e0[0] * 64 + sub * 4);
        u32x4 p1 = *(const u32x4*)(zin + (size_t)e1[0] * 64 + sub * 4);
        float w0 = (sub < 8) ? __int_as_float(e0[1]) : __int_as_float(e0[2]);
        float w1 = (sub < 8) ? __int_as_float(e1[1]) : __int_as_float(e1[2]);
        a[0] = fmaf(w0, bf_lo(p0[0]), a[0]); a[1] = fmaf(w0, bf_hi(p0[0]), a[1]);
        a[2] = fmaf(w0, bf_lo(p0[1]), a[2]); a[3] = fmaf(w0, bf_hi(p0[1]), a[3]);
        a[4] = fmaf(w0, bf_lo(p0[2]), a[4]); a[5] = fmaf(w0, bf_hi(p0[2]), a[5]);
        a[6] = fmaf(w0, bf_lo(p0[3]), a[6]); a[7] = fmaf(w0, bf_hi(p0[3]), a[7]);
        a[0] = fmaf(w1, bf_lo(p1[0]), a[0]); a[1] = fmaf(w1, bf_hi(p1[0]), a[1]);
        a[2] = fmaf(w1, bf_lo(p1[1]), a[2]); a[3] = fmaf(w1, bf_hi(p1[1]), a[3]);
        a[4] = fmaf(w1, bf_lo(p1[2]), a[4]); a[5] = fmaf(w1, bf_hi(p1[2]), a[5]);
        a[6] = fmaf(w1, bf_lo(p1[3]), a[6]); a[7] = fmaf(w1, bf_hi(p1[3]), a[7]);
    }
    for (; i < end; i += 4) {
        int idx = i + g;
        i32x4 e = __builtin_nontemporal_load(
            (const i32x4*)(edata + ((idx < end) ? idx : end - 1)));
        float wt = (idx < end) ? ((sub < 8) ? __int_as_float(e[1]) : __int_as_float(e[2])) : 0.f;
        u32x4 p = *(const u32x4*)(zin + (size_t)e[0] * 64 + sub * 4);
        a[0] = fmaf(wt, bf_lo(p[0]), a[0]); a[1] = fmaf(wt, bf_hi(p[0]), a[1]);
        a[2] = fmaf(wt, bf_lo(p[1]), a[2]); a[3] = fmaf(wt, bf_hi(p[1]), a[3]);
        a[4] = fmaf(wt, bf_lo(p[2]), a[4]); a[5] = fmaf(wt, bf_hi(p[2]), a[5]);
        a[6] = fmaf(wt, bf_lo(p[3]), a[6]); a[7] = fmaf(wt, bf_hi(p[3]), a[7]);
    }
#pragma unroll
    for (int j = 0; j < 8; ++j) {
        a[j] += __shfl_xor(a[j], 16);
        a[j] += __shfl_xor(a[j], 32);
    }
    if (lane < 16) {
        u32x4 u1 = __builtin_nontemporal_load((const u32x4*)(z1 + (size_t)w * 64 + sub * 4));
        u32x4 u2 = __builtin_nontemporal_load((const u32x4*)(z2 + (size_t)w * 64 + sub * 4));
        const float* eg = (w < NUM_USERS) ? user + (size_t)w * 64
                                          : item + (size_t)(w - NUM_USERS) * 64;
        eg += 8 * (sub & 7);
        f32x4 e0 = __builtin_nontemporal_load((const f32x4*)(eg));
        f32x4 e1 = __builtin_nontemporal_load((const f32x4*)(eg + 4));
        f32x4 o0, o1;
        o0[0] = (e0[0] + bf_lo(u1[0]) + bf_lo(u2[0]) + a[0]) * 0.25f;
        o0[1] = (e0[1] + bf_hi(u1[0]) + bf_hi(u2[0]) + a[1]) * 0.25f;
        o0[2] = (e0[2] + bf_lo(u1[1]) + bf_lo(u2[1]) + a[2]) * 0.25f;
        o0[3] = (e0[3] + bf_hi(u1[1]) + bf_hi(u2[1]) + a[3]) * 0.25f;
        o1[0] = (e1[0] + bf_lo(u1[2]) + bf_lo(u2[2]) + a[4]) * 0.25f;
        o1[1] = (e1[1] + bf_hi(u1[2]) + bf_hi(u2[2]) + a[5]) * 0.25f;
        o1[2] = (e1[2] + bf_lo(u1[3]) + bf_lo(u2[3]) + a[6]) * 0.25f;
        o1[3] = (e1[3] + bf_hi(u1[3]) + bf_hi(u2[3]) + a[7]) * 0.25f;
        float* dst = ((sub < 8) ? outx : outy) + (size_t)w * 64 + 8 * (sub & 7);
        __builtin_nontemporal_store(o0, (f32x4*)dst);
        __builtin_nontemporal_store(o1, (f32x4*)(dst + 4));
    }
}

__global__ void final_kernel(const double* __restrict__ gate_sum, float* __restrict__ out_scalar) {
    if (threadIdx.x == 0) out_scalar[0] = (float)(*gate_sum * (1.0 / (double)SS));
}

extern "C" void kernel_launch(void* const* d_in, const int* in_sizes, int n_in,
                              void* d_out, int out_size, void* d_ws, size_t ws_size,
                              hipStream_t stream) {
    const float* user = (const float*)d_in[0];
    const float* item = (const float*)d_in[1];
    const int*   rows = (const int*)d_in[2];
    const int*   cols = (const int*)d_in[3];
    const float* vals = (const float*)d_in[4];
    const int*   sidx = (const int*)d_in[5];
    const float* eps  = (const float*)d_in[6];
    const float* W1   = (const float*)d_in[7];
    const float* b1   = (const float*)d_in[8];
    const float* W2   = (const float*)d_in[9];
    const float* b2   = (const float*)d_in[10];

    float* out  = (float*)d_out;
    const size_t ND = (size_t)NN * DD;
    float* outx = out;
    float* outy = out + ND;
    float* out_scalar = out + 2 * ND;

    unsigned int* wsu = (unsigned int*)d_ws;
    unsigned int* z0 = wsu;          // half-width: NN*32 used (region sized ND)
    unsigned int* z1 = wsu + ND;
    unsigned int* z2 = wsu + 2 * ND;
    int4* edata = (int4*)(wsu + 3 * ND);
    _Float16* ego16 = (_Float16*)edata;   // aliases edata: live init->gate
    int4* buf = (int4*)z1;                // aliases z1: live scatter->to_csr
    unsigned int* regionA = wsu + 3 * ND + (size_t)EE * 4;
    int*   rowptr = (int*)regionA;                    // [0, 150016)
    float* gate   = (float*)(regionA + 150016);       // SS floats
    int*   ghist  = (int*)(regionA + 550016);         // GN ints
    int*   bsum2  = (int*)(regionA + 639680);         // GB ints
    int*   winner = (int*)(regionA + 640032);         // EE ints
    double* gate_sum = (double*)(((uintptr_t)(regionA + 640032 + EE) + 7) & ~(uintptr_t)7);

    const int B = 256;
    const int grid_init = (int)((NN * 32 + B - 1) / B);
    const int grid_E    = (EE + B - 1) / B;
    const int grid_spmm = (int)((NN * 64 + B - 1) / B);
    const int grid_init2 = (grid_E > grid_init) ? grid_E : grid_init;

    init_kernel<<<grid_init2, B, 0, stream>>>(user, item, z0, ego16, winner, rowptr, gate_sum);
    gate_kernel<<<2048, B, 0, stream>>>(ego16, rows, cols, sidx, eps,
                                        W1, b1, W2, b2, gate, gate_sum);
    bucket_count_kernel<<<NB1, B, 0, stream>>>(rows, sidx, ghist, winner);
    gscan1_kernel<<<GB, 256, 0, stream>>>(ghist, bsum2, GN);
    gscan2_kernel<<<1, 1024, 0, stream>>>(bsum2, GB);
    bucket_scatter_kernel<<<NB1, B, 0, stream>>>(rows, cols, vals, winner, gate,
                                                 ghist, bsum2, buf);
    bucket_to_csr_kernel<<<NBUCKET, B, 0, stream>>>(ghist, bsum2, buf, rowptr, edata);

    spmm_packed_kernel<<<grid_spmm, B, 0, stream>>>(rowptr, edata, z0, z1, 32, 7);
    spmm_packed_kernel<<<grid_spmm, B, 0, stream>>>(rowptr, edata, z1, z2, 64, 15);
    spmm_final_kernel<<<grid_spmm, B, 0, stream>>>(rowptr, edata, z2, z1, z2,
                                                   user, item, outx, outy);

    final_kernel<<<1, 64, 0, stream>>>(gate_sum, out_scalar);
}

// Round 7
// 474.585 us; speedup vs baseline: 1.0575x; 1.0575x over previous
//
#include <hip/hip_runtime.h>
#include <math.h>

#define NUM_USERS 100000
#define NUM_ITEMS 50000
#define NN 150000
#define DD 64
#define EE 1250000
#define SS 400000
#define TAU 0.2f
#define EDGE_BIAS 0.5f

#define NBUCKET 586     // coarse buckets (row >> 8)
#define NB1 153         // partition blocks
#define TILE 8192       // edges per partition block (153*8192 >= EE)
#define GN (NBUCKET * NB1)        // 89658 ghist entries
#define GB ((GN + 255) / 256)     // 351 scan blocks

typedef __attribute__((ext_vector_type(8))) _Float16 f16x8;
typedef __attribute__((ext_vector_type(2))) _Float16 f16x2;
typedef __attribute__((ext_vector_type(4))) float f32x4;

#define LDW 136  // f16 LDS row stride for gate W1 prologue

// bf16 helpers (RNE, finite inputs)
__device__ __forceinline__ unsigned int pack_bf16(float lo, float hi) {
    unsigned int a = __float_as_uint(lo), b = __float_as_uint(hi);
    a += 0x7fffu + ((a >> 16) & 1u);
    b += 0x7fffu + ((b >> 16) & 1u);
    return (a >> 16) | (b & 0xffff0000u);
}
__device__ __forceinline__ float bf_lo(unsigned int u) { return __uint_as_float(u << 16); }
__device__ __forceinline__ float bf_hi(unsigned int u) { return __uint_as_float(u & 0xffff0000u); }

// ---------------------------------------------------------------------------
// init: half-width z0 (chains identical at l=0), f16 ego copy for gate,
// winner=-1, rowptr[NN], gate_sum=0.
// ---------------------------------------------------------------------------
__global__ void init_kernel(const float* __restrict__ user, const float* __restrict__ item,
                            unsigned int* __restrict__ z0h, _Float16* __restrict__ ego16,
                            int* __restrict__ winner, int* __restrict__ rowptr,
                            double* __restrict__ gate_sum) {
    int j = blockIdx.x * blockDim.x + threadIdx.x;
    if (j < NN * 32) {
        int n = j >> 5, dp = j & 31;
        const float* ego = (n < NUM_USERS) ? user + (size_t)n * 64
                                           : item + (size_t)(n - NUM_USERS) * 64;
        float2 e = *(const float2*)(ego + 2 * dp);
        z0h[j] = pack_bf16(e.x, e.y);
        f16x2 h;
        h[0] = (_Float16)e.x;
        h[1] = (_Float16)e.y;
        *(f16x2*)(ego16 + (size_t)n * 64 + 2 * dp) = h;
    }
    if (j < EE) winner[j] = -1;
    if (j == 0) { rowptr[NN] = EE; *gate_sum = 0.0; }
}

// ---------------------------------------------------------------------------
// gate MLP via f16 MFMA, barrier-free direct-gather, fast-math epilogue
// ---------------------------------------------------------------------------
__global__ __launch_bounds__(256) void gate_kernel(
        const _Float16* __restrict__ ego16,
        const int* __restrict__ rows, const int* __restrict__ cols,
        const int* __restrict__ sidx, const float* __restrict__ eps,
        const float* __restrict__ W1, const float* __restrict__ b1,
        const float* __restrict__ W2, const float* __restrict__ b2,
        float* __restrict__ gate, double* __restrict__ gate_sum) {
    __shared__ _Float16 sh[64 * LDW];
    __shared__ double sdq[4];

    const int t    = threadIdx.x;
    const int lane = t & 63;
    const int w    = t >> 6;
    const int col  = lane & 15;
    const int quad = lane >> 4;

    for (int idx = t; idx < 8192; idx += 256) {
        int k = idx >> 6, n = idx & 63;
        sh[n * LDW + k] = (_Float16)W1[idx];
    }
    float b1v[4];
#pragma unroll
    for (int nt = 0; nt < 4; ++nt) b1v[nt] = b1[nt * 16 + col];
    float w2v[4];
#pragma unroll
    for (int nt = 0; nt < 4; ++nt) w2v[nt] = W2[nt * 16 + col];
    const float b2v = b2[0];
    __syncthreads();

    f16x8 bfrag[4][4];
#pragma unroll
    for (int nt = 0; nt < 4; ++nt)
#pragma unroll
        for (int kk = 0; kk < 4; ++kk)
            bfrag[nt][kk] = *(const f16x8*)&sh[(nt * 16 + col) * LDW + kk * 32 + quad * 8];

    double partial = 0.0;
    const int nwaves = gridDim.x * 4;
    const int wid = blockIdx.x * 4 + w;

    for (int grp = wid; grp < SS / 16; grp += nwaves) {
        const int gbase = grp * 16;
        const int sid = sidx[gbase + col];
        const int su = rows[sid];
        const int sv = cols[sid];
        const _Float16* pu = ego16 + (size_t)su * 64 + quad * 8;
        const _Float16* pv = ego16 + (size_t)sv * 64 + quad * 8;
        f16x8 a0 = *(const f16x8*)(pu);
        f16x8 a1 = *(const f16x8*)(pu + 32);
        f16x8 a2 = *(const f16x8*)(pv);
        f16x8 a3 = *(const f16x8*)(pv + 32);

        f32x4 acc[4] = {};
#pragma unroll
        for (int nt = 0; nt < 4; ++nt) {
            acc[nt] = __builtin_amdgcn_mfma_f32_16x16x32_f16(a0, bfrag[nt][0], acc[nt], 0, 0, 0);
            acc[nt] = __builtin_amdgcn_mfma_f32_16x16x32_f16(a1, bfrag[nt][1], acc[nt], 0, 0, 0);
            acc[nt] = __builtin_amdgcn_mfma_f32_16x16x32_f16(a2, bfrag[nt][2], acc[nt], 0, 0, 0);
            acc[nt] = __builtin_amdgcn_mfma_f32_16x16x32_f16(a3, bfrag[nt][3], acc[nt], 0, 0, 0);
        }

        float p[4];
#pragma unroll
        for (int r = 0; r < 4; ++r) {
            float sum = 0.f;
#pragma unroll
            for (int nt = 0; nt < 4; ++nt)
                sum = fmaf(fmaxf(acc[nt][r] + b1v[nt], 0.f), w2v[nt], sum);
#pragma unroll
            for (int off = 8; off >= 1; off >>= 1) sum += __shfl_xor(sum, off);
            p[r] = sum + b2v;
        }
        if (col == 0) {
            const int sb = gbase + quad * 4;
            float4 ev4 = *(const float4*)(eps + sb);
            float g4[4];
            const float evs[4] = {ev4.x, ev4.y, ev4.z, ev4.w};
#pragma unroll
            for (int r = 0; r < 4; ++r) {
                float ev  = evs[r] * (1.f - 2e-6f) + 1e-6f;
                float gum = __logf(ev) - __logf(1.f - ev);
                float zz  = (p[r] + gum) * (1.f / TAU);
                float g   = __builtin_amdgcn_rcpf(1.f + __expf(-zz)) + EDGE_BIAS;
                g4[r] = g;
                partial += (double)g;
            }
            *(float4*)(gate + sb) = make_float4(g4[0], g4[1], g4[2], g4[3]);
        }
    }

#pragma unroll
    for (int off = 32; off >= 1; off >>= 1) partial += __shfl_xor(partial, off);
    if (lane == 0) sdq[w] = partial;
    __syncthreads();
    if (t == 0) atomicAdd(gate_sum, sdq[0] + sdq[1] + sdq[2] + sdq[3]);
}

// ---------------------------------------------------------------------------
// Deterministic radix-partition scatter
// ---------------------------------------------------------------------------
__global__ __launch_bounds__(256) void bucket_count_kernel(
        const int* __restrict__ rows, const int* __restrict__ sidx,
        int* __restrict__ ghist, int* __restrict__ winner) {
    __shared__ int h[NBUCKET];
    const int t = threadIdx.x;
    for (int i = t; i < NBUCKET; i += 256) h[i] = 0;
    __syncthreads();
    const int base = blockIdx.x * TILE;
    const int end = (base + TILE < EE) ? base + TILE : EE;
    for (int i = base + t; i < end; i += 256) atomicAdd(&h[rows[i] >> 8], 1);
    const int gt = blockIdx.x * 256 + t;
    for (int s = gt; s < SS; s += NB1 * 256) atomicMax(&winner[sidx[s]], s);
    __syncthreads();
    for (int i = t; i < NBUCKET; i += 256) ghist[i * NB1 + blockIdx.x] = h[i];
}

__global__ void gscan1_kernel(int* __restrict__ data, int* __restrict__ bsum, int N) {
    __shared__ int sh[256];
    int tid = threadIdx.x;
    int i = blockIdx.x * 256 + tid;
    int v = (i < N) ? data[i] : 0;
    sh[tid] = v;
    __syncthreads();
    for (int off = 1; off < 256; off <<= 1) {
        int tv = (tid >= off) ? sh[tid - off] : 0;
        __syncthreads();
        sh[tid] += tv;
        __syncthreads();
    }
    if (i < N) data[i] = sh[tid] - v;
    if (tid == 255) bsum[blockIdx.x] = sh[255];
}

__global__ void gscan2_kernel(int* __restrict__ bsum, int NB) {
    __shared__ int sh[1024];
    int tid = threadIdx.x;
    int v = (tid < NB) ? bsum[tid] : 0;
    sh[tid] = v;
    __syncthreads();
    for (int off = 1; off < 1024; off <<= 1) {
        int tv = (tid >= off) ? sh[tid - off] : 0;
        __syncthreads();
        sh[tid] += tv;
        __syncthreads();
    }
    if (tid < NB) bsum[tid] = sh[tid] - v;
}

// gscan3 folded into consumers: final prefix = ghist[i] + bsum2[i>>8].

__global__ __launch_bounds__(256) void bucket_scatter_kernel(
        const int* __restrict__ rows, const int* __restrict__ cols,
        const float* __restrict__ vals,
        const int* __restrict__ winner, const float* __restrict__ gate,
        const int* __restrict__ ghist, const int* __restrict__ bsum2,
        int4* __restrict__ buf) {
    __shared__ int sbase[NBUCKET];
    const int t = threadIdx.x;
    for (int i = t; i < NBUCKET; i += 256) {
        int idx = i * NB1 + blockIdx.x;
        sbase[i] = ghist[idx] + bsum2[idx >> 8];
    }
    __syncthreads();
    const int base = blockIdx.x * TILE;
    const int end = (base + TILE < EE) ? base + TILE : EE;
    for (int e = base + t; e < end; e += 256) {
        int r = rows[e];
        float v = vals[e];
        int wn = winner[e];
        float mv = (wn >= 0) ? v * gate[wn] : v;
        int pos = atomicAdd(&sbase[r >> 8], 1);
        buf[pos] = make_int4(r, cols[e], __float_as_int(v), __float_as_int(mv));
    }
}

// bucket -> CSR. Writes the SPLIT edge format: ecol (4B col) + ewv (8B
// {val, mval}) — drops the 4B pad that cost 25% of every edge stream.
__global__ __launch_bounds__(256) void bucket_to_csr_kernel(
        const int* __restrict__ ghist, const int* __restrict__ bsum2,
        const int4* __restrict__ buf,
        int* __restrict__ rowptr, int* __restrict__ ecol, float2* __restrict__ ewv) {
    __shared__ int sh[256];
    const int b = blockIdx.x;
    const int t = threadIdx.x;
    const int i0 = b * NB1;
    const int i1 = (b + 1) * NB1;
    const int rbeg = ghist[i0] + bsum2[i0 >> 8];
    const int rend = (b + 1 < NBUCKET) ? ghist[i1] + bsum2[i1 >> 8] : EE;
    sh[t] = 0;
    __syncthreads();
    for (int i = rbeg + t; i < rend; i += 256) atomicAdd(&sh[buf[i].x & 255], 1);
    __syncthreads();
    int cnt = sh[t];
    for (int off = 1; off < 256; off <<= 1) {
        int tv = (t >= off) ? sh[t - off] : 0;
        __syncthreads();
        sh[t] += tv;
        __syncthreads();
    }
    int rowbase = rbeg + sh[t] - cnt;
    int r = (b << 8) + t;
    if (r < NN) rowptr[r] = rowbase;
    __syncthreads();
    sh[t] = rowbase;
    __syncthreads();
    for (int i = rbeg + t; i < rend; i += 256) {
        int4 ed = buf[i];
        int pos = atomicAdd(&sh[ed.x & 255], 1);
        ecol[pos] = ed.y;
        ewv[pos] = make_float2(__int_as_float(ed.z), __int_as_float(ed.w));
    }
}

// ---------------------------------------------------------------------------
// packed dual-chain gather-SpMM, split edge streams (ecol + ewv), NT hints
// fully reverted (R6: nt loads bypass L2 reuse on gfx950 — regressed 18%).
// ---------------------------------------------------------------------------
__global__ __launch_bounds__(256) void spmm_packed_kernel(
        const int* __restrict__ rowptr,
        const int* __restrict__ ecol, const float2* __restrict__ ewv,
        const unsigned int* __restrict__ zin, unsigned int* __restrict__ zout,
        int zstride, int zmask) {
    int w = (blockIdx.x * blockDim.x + threadIdx.x) >> 6;
    if (w >= NN) return;
    const int lane = threadIdx.x & 63;
    const int g    = lane >> 4;
    const int sub  = lane & 15;
    const int sq   = (sub & zmask) * 4;
    const int beg = rowptr[w], end = rowptr[w + 1];

    float a[8] = {0.f, 0.f, 0.f, 0.f, 0.f, 0.f, 0.f, 0.f};
    int i = beg;
    for (; i + 8 <= end; i += 8) {
        int c0 = ecol[i + g];
        int c1 = ecol[i + 4 + g];
        float2 wv0 = ewv[i + g];
        float2 wv1 = ewv[i + 4 + g];
        uint4 p0 = *(const uint4*)(zin + (size_t)c0 * zstride + sq);
        uint4 p1 = *(const uint4*)(zin + (size_t)c1 * zstride + sq);
        float w0 = (sub < 8) ? wv0.x : wv0.y;
        float w1 = (sub < 8) ? wv1.x : wv1.y;
        a[0] = fmaf(w0, bf_lo(p0.x), a[0]); a[1] = fmaf(w0, bf_hi(p0.x), a[1]);
        a[2] = fmaf(w0, bf_lo(p0.y), a[2]); a[3] = fmaf(w0, bf_hi(p0.y), a[3]);
        a[4] = fmaf(w0, bf_lo(p0.z), a[4]); a[5] = fmaf(w0, bf_hi(p0.z), a[5]);
        a[6] = fmaf(w0, bf_lo(p0.w), a[6]); a[7] = fmaf(w0, bf_hi(p0.w), a[7]);
        a[0] = fmaf(w1, bf_lo(p1.x), a[0]); a[1] = fmaf(w1, bf_hi(p1.x), a[1]);
        a[2] = fmaf(w1, bf_lo(p1.y), a[2]); a[3] = fmaf(w1, bf_hi(p1.y), a[3]);
        a[4] = fmaf(w1, bf_lo(p1.z), a[4]); a[5] = fmaf(w1, bf_hi(p1.z), a[5]);
        a[6] = fmaf(w1, bf_lo(p1.w), a[6]); a[7] = fmaf(w1, bf_hi(p1.w), a[7]);
    }
    for (; i < end; i += 4) {
        int idx = i + g;
        int ic = (idx < end) ? idx : end - 1;
        int c = ecol[ic];
        float2 wv = ewv[ic];
        float wt = (idx < end) ? ((sub < 8) ? wv.x : wv.y) : 0.f;
        uint4 p = *(const uint4*)(zin + (size_t)c * zstride + sq);
        a[0] = fmaf(wt, bf_lo(p.x), a[0]); a[1] = fmaf(wt, bf_hi(p.x), a[1]);
        a[2] = fmaf(wt, bf_lo(p.y), a[2]); a[3] = fmaf(wt, bf_hi(p.y), a[3]);
        a[4] = fmaf(wt, bf_lo(p.z), a[4]); a[5] = fmaf(wt, bf_hi(p.z), a[5]);
        a[6] = fmaf(wt, bf_lo(p.w), a[6]); a[7] = fmaf(wt, bf_hi(p.w), a[7]);
    }
#pragma unroll
    for (int j = 0; j < 8; ++j) {
        a[j] += __shfl_xor(a[j], 16);
        a[j] += __shfl_xor(a[j], 32);
    }
    if (lane < 16) {
        uint4 o;
        o.x = pack_bf16(a[0], a[1]);
        o.y = pack_bf16(a[2], a[3]);
        o.z = pack_bf16(a[4], a[5]);
        o.w = pack_bf16(a[6], a[7]);
        *(uint4*)(zout + (size_t)w * 64 + sub * 4) = o;
    }
}

// ---------------------------------------------------------------------------
// final SpMM layer fused with fold (split edge streams, plain loads/stores)
// ---------------------------------------------------------------------------
__global__ __launch_bounds__(256) void spmm_final_kernel(
        const int* __restrict__ rowptr,
        const int* __restrict__ ecol, const float2* __restrict__ ewv,
        const unsigned int* __restrict__ zin,
        const unsigned int* __restrict__ z1, const unsigned int* __restrict__ z2,
        const float* __restrict__ user, const float* __restrict__ item,
        float* __restrict__ outx, float* __restrict__ outy) {
    int w = (blockIdx.x * blockDim.x + threadIdx.x) >> 6;
    if (w >= NN) return;
    const int lane = threadIdx.x & 63;
    const int g    = lane >> 4;
    const int sub  = lane & 15;
    const int beg = rowptr[w], end = rowptr[w + 1];

    float a[8] = {0.f, 0.f, 0.f, 0.f, 0.f, 0.f, 0.f, 0.f};
    int i = beg;
    for (; i + 8 <= end; i += 8) {
        int c0 = ecol[i + g];
        int c1 = ecol[i + 4 + g];
        float2 wv0 = ewv[i + g];
        float2 wv1 = ewv[i + 4 + g];
        uint4 p0 = *(const uint4*)(zin + (size_t)c0 * 64 + sub * 4);
        uint4 p1 = *(const uint4*)(zin + (size_t)c1 * 64 + sub * 4);
        float w0 = (sub < 8) ? wv0.x : wv0.y;
        float w1 = (sub < 8) ? wv1.x : wv1.y;
        a[0] = fmaf(w0, bf_lo(p0.x), a[0]); a[1] = fmaf(w0, bf_hi(p0.x), a[1]);
        a[2] = fmaf(w0, bf_lo(p0.y), a[2]); a[3] = fmaf(w0, bf_hi(p0.y), a[3]);
        a[4] = fmaf(w0, bf_lo(p0.z), a[4]); a[5] = fmaf(w0, bf_hi(p0.z), a[5]);
        a[6] = fmaf(w0, bf_lo(p0.w), a[6]); a[7] = fmaf(w0, bf_hi(p0.w), a[7]);
        a[0] = fmaf(w1, bf_lo(p1.x), a[0]); a[1] = fmaf(w1, bf_hi(p1.x), a[1]);
        a[2] = fmaf(w1, bf_lo(p1.y), a[2]); a[3] = fmaf(w1, bf_hi(p1.y), a[3]);
        a[4] = fmaf(w1, bf_lo(p1.z), a[4]); a[5] = fmaf(w1, bf_hi(p1.z), a[5]);
        a[6] = fmaf(w1, bf_lo(p1.w), a[6]); a[7] = fmaf(w1, bf_hi(p1.w), a[7]);
    }
    for (; i < end; i += 4) {
        int idx = i + g;
        int ic = (idx < end) ? idx : end - 1;
        int c = ecol[ic];
        float2 wv = ewv[ic];
        float wt = (idx < end) ? ((sub < 8) ? wv.x : wv.y) : 0.f;
        uint4 p = *(const uint4*)(zin + (size_t)c * 64 + sub * 4);
        a[0] = fmaf(wt, bf_lo(p.x), a[0]); a[1] = fmaf(wt, bf_hi(p.x), a[1]);
        a[2] = fmaf(wt, bf_lo(p.y), a[2]); a[3] = fmaf(wt, bf_hi(p.y), a[3]);
        a[4] = fmaf(wt, bf_lo(p.z), a[4]); a[5] = fmaf(wt, bf_hi(p.z), a[5]);
        a[6] = fmaf(wt, bf_lo(p.w), a[6]); a[7] = fmaf(wt, bf_hi(p.w), a[7]);
    }
#pragma unroll
    for (int j = 0; j < 8; ++j) {
        a[j] += __shfl_xor(a[j], 16);
        a[j] += __shfl_xor(a[j], 32);
    }
    if (lane < 16) {
        uint4 u1 = *(const uint4*)(z1 + (size_t)w * 64 + sub * 4);
        uint4 u2 = *(const uint4*)(z2 + (size_t)w * 64 + sub * 4);
        const float* eg = (w < NUM_USERS) ? user + (size_t)w * 64
                                          : item + (size_t)(w - NUM_USERS) * 64;
        eg += 8 * (sub & 7);
        float4 e0 = *(const float4*)(eg);
        float4 e1 = *(const float4*)(eg + 4);
        float4 o0, o1;
        o0.x = (e0.x + bf_lo(u1.x) + bf_lo(u2.x) + a[0]) * 0.25f;
        o0.y = (e0.y + bf_hi(u1.x) + bf_hi(u2.x) + a[1]) * 0.25f;
        o0.z = (e0.z + bf_lo(u1.y) + bf_lo(u2.y) + a[2]) * 0.25f;
        o0.w = (e0.w + bf_hi(u1.y) + bf_hi(u2.y) + a[3]) * 0.25f;
        o1.x = (e1.x + bf_lo(u1.z) + bf_lo(u2.z) + a[4]) * 0.25f;
        o1.y = (e1.y + bf_hi(u1.z) + bf_hi(u2.z) + a[5]) * 0.25f;
        o1.z = (e1.z + bf_lo(u1.w) + bf_lo(u2.w) + a[6]) * 0.25f;
        o1.w = (e1.w + bf_hi(u1.w) + bf_hi(u2.w) + a[7]) * 0.25f;
        float* dst = ((sub < 8) ? outx : outy) + (size_t)w * 64 + 8 * (sub & 7);
        *(float4*)dst = o0;
        *(float4*)(dst + 4) = o1;
    }
}

__global__ void final_kernel(const double* __restrict__ gate_sum, float* __restrict__ out_scalar) {
    if (threadIdx.x == 0) out_scalar[0] = (float)(*gate_sum * (1.0 / (double)SS));
}

extern "C" void kernel_launch(void* const* d_in, const int* in_sizes, int n_in,
                              void* d_out, int out_size, void* d_ws, size_t ws_size,
                              hipStream_t stream) {
    const float* user = (const float*)d_in[0];
    const float* item = (const float*)d_in[1];
    const int*   rows = (const int*)d_in[2];
    const int*   cols = (const int*)d_in[3];
    const float* vals = (const float*)d_in[4];
    const int*   sidx = (const int*)d_in[5];
    const float* eps  = (const float*)d_in[6];
    const float* W1   = (const float*)d_in[7];
    const float* b1   = (const float*)d_in[8];
    const float* W2   = (const float*)d_in[9];
    const float* b2   = (const float*)d_in[10];

    float* out  = (float*)d_out;
    const size_t ND = (size_t)NN * DD;
    float* outx = out;
    float* outy = out + ND;
    float* out_scalar = out + 2 * ND;

    unsigned int* wsu = (unsigned int*)d_ws;
    unsigned int* z0 = wsu;          // half-width: NN*32 used (region sized ND)
    unsigned int* z1 = wsu + ND;
    unsigned int* z2 = wsu + 2 * ND;
    // edge region (sized EE*4 u32 = 20MB): split streams ecol (EE) + ewv (2*EE)
    unsigned int* eregion = wsu + 3 * ND;
    int*    ecol = (int*)eregion;
    float2* ewv  = (float2*)(eregion + EE);
    _Float16* ego16 = (_Float16*)eregion;  // aliases edge region: live init->gate
    int4* buf = (int4*)z1;                 // aliases z1: live scatter->to_csr
    unsigned int* regionA = wsu + 3 * ND + (size_t)EE * 4;
    int*   rowptr = (int*)regionA;                    // [0, 150016)
    float* gate   = (float*)(regionA + 150016);       // SS floats
    int*   ghist  = (int*)(regionA + 550016);         // GN ints
    int*   bsum2  = (int*)(regionA + 639680);         // GB ints
    int*   winner = (int*)(regionA + 640032);         // EE ints
    double* gate_sum = (double*)(((uintptr_t)(regionA + 640032 + EE) + 7) & ~(uintptr_t)7);

    const int B = 256;
    const int grid_init = (int)((NN * 32 + B - 1) / B);
    const int grid_E    = (EE + B - 1) / B;
    const int grid_spmm = (int)((NN * 64 + B - 1) / B);
    const int grid_init2 = (grid_E > grid_init) ? grid_E : grid_init;

    init_kernel<<<grid_init2, B, 0, stream>>>(user, item, z0, ego16, winner, rowptr, gate_sum);
    gate_kernel<<<2048, B, 0, stream>>>(ego16, rows, cols, sidx, eps,
                                        W1, b1, W2, b2, gate, gate_sum);
    bucket_count_kernel<<<NB1, B, 0, stream>>>(rows, sidx, ghist, winner);
    gscan1_kernel<<<GB, 256, 0, stream>>>(ghist, bsum2, GN);
    gscan2_kernel<<<1, 1024, 0, stream>>>(bsum2, GB);
    bucket_scatter_kernel<<<NB1, B, 0, stream>>>(rows, cols, vals, winner, gate,
                                                 ghist, bsum2, buf);
    bucket_to_csr_kernel<<<NBUCKET, B, 0, stream>>>(ghist, bsum2, buf, rowptr, ecol, ewv);

    spmm_packed_kernel<<<grid_spmm, B, 0, stream>>>(rowptr, ecol, ewv, z0, z1, 32, 7);
    spmm_packed_kernel<<<grid_spmm, B, 0, stream>>>(rowptr, ecol, ewv, z1, z2, 64, 15);
    spmm_final_kernel<<<grid_spmm, B, 0, stream>>>(rowptr, ecol, ewv, z2, z1, z2,
                                                   user, item, outx, outy);

    final_kernel<<<1, 64, 0, stream>>>(gate_sum, out_scalar);
}